// Round 1
// baseline (680.288 us; speedup 1.0000x reference)
//
#include <hip/hip_runtime.h>

// ============================================================================
// Cosine-sim top-5 weighted gather, N=16384, D=256.
//   sim = normalize(A) @ normalize(A)^T ; top5 per row; out = mean(w^2 * A[idx])
//
// Strategy: split-bf16 (hi+lo) 3-term MFMA GEMM for sims (err ~1e-6),
// fused per-lane register top-8 per j-range (4 ranges), fp64 rescore of the
// merged top-8, then weighted gather. Everything is L2/L3 resident.
// ============================================================================

#define N_ROWS 16384
#define DIM 256
#define RANGES 4              // j-split of the grid
#define CANDS 32              // 4 ranges * 8 candidates

using bf16x8 = __attribute__((ext_vector_type(8))) short;   // 8 bf16 (4 VGPRs)
using f32x16 = __attribute__((ext_vector_type(16))) float;  // 32x32 acc

static __device__ __forceinline__ unsigned short f32_bf16_rne(float f) {
  unsigned u = __float_as_uint(f);
  u += 0x7fffu + ((u >> 16) & 1u);      // round-to-nearest-even (no NaN inputs)
  return (unsigned short)(u >> 16);
}

// insert v into ascending sorted tv[0..7] (drop old min). Precondition v>tv[0].
static __device__ __forceinline__ void insert8(float tv[8], int ti[8], float v, int j) {
#pragma unroll
  for (int p = 0; p < 7; ++p) {
    const bool shift = (tv[p + 1] < v);          // element p takes p+1's value
    const bool put   = !shift && (tv[p] < v);    // v lands here
    const float nv = shift ? tv[p + 1] : (put ? v : tv[p]);
    const int   ni = shift ? ti[p + 1] : (put ? j : ti[p]);
    tv[p] = nv; ti[p] = ni;
  }
  if (tv[7] < v) { tv[7] = v; ti[7] = j; }
}

// ---------------------------------------------------------------------------
// Kernel 1: fp64 row norms; write normalized features as bf16 hi/lo pairs in
// MFMA-packed layout: elem(row,k) -> [row>>5][k>>4][(k>>3)&1][row&31][k&7]
// so a 32x32x16 A/B fragment load is lane-contiguous 16B (1 KiB/wave/load).
// ---------------------------------------------------------------------------
__global__ __launch_bounds__(256) void prep_kernel(
    const float* __restrict__ feat,
    unsigned short* __restrict__ phi, unsigned short* __restrict__ plo,
    double* __restrict__ invn) {
  const int tid = threadIdx.x;
  const int sub = tid >> 5;          // 8 sub-groups of 32 lanes, one row each
  const int l32 = tid & 31;
  const int row = blockIdx.x * 8 + sub;

  const float4 a = *reinterpret_cast<const float4*>(feat + (size_t)row * DIM + l32 * 8);
  const float4 b = *reinterpret_cast<const float4*>(feat + (size_t)row * DIM + l32 * 8 + 4);
  double s = (double)a.x * a.x + (double)a.y * a.y + (double)a.z * a.z + (double)a.w * a.w +
             (double)b.x * b.x + (double)b.y * b.y + (double)b.z * b.z + (double)b.w * b.w;
#pragma unroll
  for (int m = 16; m >= 1; m >>= 1) s += __shfl_xor(s, m);   // within 32-lane group
  const double inv = 1.0 / sqrt(s);
  if (l32 == 0) invn[row] = inv;

  float nf[8] = {a.x, a.y, a.z, a.w, b.x, b.y, b.z, b.w};
  unsigned hi[8], lo[8];
#pragma unroll
  for (int e = 0; e < 8; ++e) {
    const float x  = (float)((double)nf[e] * inv);
    const unsigned short h = f32_bf16_rne(x);
    const float hf = __uint_as_float(((unsigned)h) << 16);
    hi[e] = h;
    lo[e] = f32_bf16_rne(x - hf);   // exact residual, then RNE to bf16
  }
  // lane l32 owns elements k = 8*l32 .. 8*l32+7  ->  one contiguous 16B chunk
  const size_t off = (size_t)(row >> 5) * 8192 + (size_t)(l32 >> 1) * 512 +
                     (size_t)(l32 & 1) * 256 + (size_t)(row & 31) * 8;
  uint4 uh, ul;
  uh.x = hi[0] | (hi[1] << 16); uh.y = hi[2] | (hi[3] << 16);
  uh.z = hi[4] | (hi[5] << 16); uh.w = hi[6] | (hi[7] << 16);
  ul.x = lo[0] | (lo[1] << 16); ul.y = lo[2] | (lo[3] << 16);
  ul.z = lo[4] | (lo[5] << 16); ul.w = lo[6] | (lo[7] << 16);
  *reinterpret_cast<uint4*>(phi + off) = uh;
  *reinterpret_cast<uint4*>(plo + off) = ul;
}

// ---------------------------------------------------------------------------
// Kernel 2: fused split-bf16 GEMM + per-row top-8 (per j-range).
// Block: 4 waves, SAME 64 query rows i (L1 reuse), wave w owns j-strip of 64.
// Computes D[j][i] = sum_k feat_n[j][k] * feat_n[i][k] so each lane's acc regs
// belong to exactly one i  ->  per-lane register top-8, no cross-lane in loop.
// ---------------------------------------------------------------------------
__global__ __launch_bounds__(256, 2) void sim_topk_kernel(
    const unsigned short* __restrict__ phi, const unsigned short* __restrict__ plo,
    float* __restrict__ cval, int* __restrict__ cidx) {
  __shared__ float sval[64][64];
  __shared__ int   sidx[64][64];

  const int tid  = threadIdx.x;
  const int wave = tid >> 6;
  const int lane = tid & 63;
  const int hi   = lane >> 5;
  const int iblk = blockIdx.x;     // 64 query rows: iblk*64 ..
  const int range = blockIdx.y;    // j in [range*4096, range*4096+4096)

  // query (B-operand) fragment base offsets, panels iblk*2 and iblk*2+1
  const size_t ioff0 = (size_t)(iblk * 2 + 0) * 8192 + (size_t)lane * 8;
  const size_t ioff1 = (size_t)(iblk * 2 + 1) * 8192 + (size_t)lane * 8;

  float tv0[8], tv1[8]; int ti0[8], ti1[8];
#pragma unroll
  for (int c = 0; c < 8; ++c) { tv0[c] = -1e30f; tv1[c] = -1e30f; ti0[c] = 0; ti1[c] = 0; }

  for (int jt = 0; jt < 16; ++jt) {
    const int jbase = range * 4096 + jt * 256 + wave * 64;
    const size_t joff0 = (size_t)((jbase >> 5) + 0) * 8192 + (size_t)lane * 8;
    const size_t joff1 = (size_t)((jbase >> 5) + 1) * 8192 + (size_t)lane * 8;

    f32x16 acc00, acc01, acc10, acc11;   // [jf][if]
#pragma unroll
    for (int r = 0; r < 16; ++r) { acc00[r] = 0.f; acc01[r] = 0.f; acc10[r] = 0.f; acc11[r] = 0.f; }

#pragma unroll 2
    for (int kc = 0; kc < 16; ++kc) {
      const size_t ks = (size_t)kc * 512;
      const bf16x8 aj0h = *reinterpret_cast<const bf16x8*>(phi + joff0 + ks);
      const bf16x8 aj1h = *reinterpret_cast<const bf16x8*>(phi + joff1 + ks);
      const bf16x8 aj0l = *reinterpret_cast<const bf16x8*>(plo + joff0 + ks);
      const bf16x8 aj1l = *reinterpret_cast<const bf16x8*>(plo + joff1 + ks);
      const bf16x8 bi0h = *reinterpret_cast<const bf16x8*>(phi + ioff0 + ks);
      const bf16x8 bi1h = *reinterpret_cast<const bf16x8*>(phi + ioff1 + ks);
      const bf16x8 bi0l = *reinterpret_cast<const bf16x8*>(plo + ioff0 + ks);
      const bf16x8 bi1l = *reinterpret_cast<const bf16x8*>(plo + ioff1 + ks);
      // hi*hi
      acc00 = __builtin_amdgcn_mfma_f32_32x32x16_bf16(aj0h, bi0h, acc00, 0, 0, 0);
      acc01 = __builtin_amdgcn_mfma_f32_32x32x16_bf16(aj0h, bi1h, acc01, 0, 0, 0);
      acc10 = __builtin_amdgcn_mfma_f32_32x32x16_bf16(aj1h, bi0h, acc10, 0, 0, 0);
      acc11 = __builtin_amdgcn_mfma_f32_32x32x16_bf16(aj1h, bi1h, acc11, 0, 0, 0);
      // hi*lo
      acc00 = __builtin_amdgcn_mfma_f32_32x32x16_bf16(aj0h, bi0l, acc00, 0, 0, 0);
      acc01 = __builtin_amdgcn_mfma_f32_32x32x16_bf16(aj0h, bi1l, acc01, 0, 0, 0);
      acc10 = __builtin_amdgcn_mfma_f32_32x32x16_bf16(aj1h, bi0l, acc10, 0, 0, 0);
      acc11 = __builtin_amdgcn_mfma_f32_32x32x16_bf16(aj1h, bi1l, acc11, 0, 0, 0);
      // lo*hi
      acc00 = __builtin_amdgcn_mfma_f32_32x32x16_bf16(aj0l, bi0h, acc00, 0, 0, 0);
      acc01 = __builtin_amdgcn_mfma_f32_32x32x16_bf16(aj0l, bi1h, acc01, 0, 0, 0);
      acc10 = __builtin_amdgcn_mfma_f32_32x32x16_bf16(aj1l, bi0h, acc10, 0, 0, 0);
      acc11 = __builtin_amdgcn_mfma_f32_32x32x16_bf16(aj1l, bi1h, acc11, 0, 0, 0);
    }

    // top-k update. D layout: col(lane&31)=i_local, row=(r&3)+8*(r>>2)+4*hi = j_local
#pragma unroll
    for (int r = 0; r < 16; ++r) {
      const int jl = (r & 3) + 8 * (r >> 2) + 4 * hi;
      { const float v = acc00[r]; if (v > tv0[0]) insert8(tv0, ti0, v, jbase + jl); }
      { const float v = acc01[r]; if (v > tv1[0]) insert8(tv1, ti1, v, jbase + jl); }
      { const float v = acc10[r]; if (v > tv0[0]) insert8(tv0, ti0, v, jbase + 32 + jl); }
      { const float v = acc11[r]; if (v > tv1[0]) insert8(tv1, ti1, v, jbase + 32 + jl); }
    }
    __syncthreads();   // keep waves paced for i-fragment L1 reuse
  }

  // ---- merge 8 partial top-8s per row (4 waves x 2 lane-halves) via LDS ----
  {
    const int slot = wave * 16 + hi * 8;
    const int r0 = (lane & 31);          // state tv0 covers i_local = r0
    const int r1 = 32 + (lane & 31);     // state tv1 covers i_local = 32+r0
#pragma unroll
    for (int c = 0; c < 8; ++c) {
      sval[slot + c][r0] = tv0[c]; sidx[slot + c][r0] = ti0[c];
      sval[slot + c][r1] = tv1[c]; sidx[slot + c][r1] = ti1[c];
    }
  }
  __syncthreads();
  if (tid < 64) {
    float bv[8]; int bi[8];
#pragma unroll
    for (int c = 0; c < 8; ++c) { bv[c] = -1e30f; bi[c] = 0; }
    for (int k = 0; k < 64; ++k) {
      const float v = sval[k][tid];
      if (v > bv[0]) insert8(bv, bi, v, sidx[k][tid]);
    }
    const size_t base = (size_t)(iblk * 64 + tid) * CANDS + range * 8;
#pragma unroll
    for (int c = 0; c < 8; ++c) { cval[base + c] = bv[c]; cidx[base + c] = bi[c]; }
  }
}

// ---------------------------------------------------------------------------
// Kernel 3: per row (one wave): merge 32 candidates -> top-8 by stage-1 value,
// fp64 rescore, top-5, weights^2, fused weighted gather.
// ---------------------------------------------------------------------------
__global__ __launch_bounds__(256) void finalize_kernel(
    const float* __restrict__ feat, const double* __restrict__ invn,
    const float* __restrict__ cval, const int* __restrict__ cidx,
    float* __restrict__ out) {
  const int wave = threadIdx.x >> 6, lane = threadIdx.x & 63;
  const int row = blockIdx.x * 4 + wave;

  float v = -1e30f; int id = -1;
  if (lane < 32) {
    v  = cval[(size_t)row * CANDS + lane];
    id = cidx[(size_t)row * CANDS + lane];
  }
  // top-8 by stage-1 value via repeated wave argmax
  int sel[8];
#pragma unroll
  for (int c = 0; c < 8; ++c) {
    float mv = v; int mi = id;
#pragma unroll
    for (int m = 32; m >= 1; m >>= 1) {
      const float ov = __shfl_xor(mv, m); const int oi = __shfl_xor(mi, m);
      if (ov > mv || (ov == mv && oi > mi)) { mv = ov; mi = oi; }
    }
    sel[c] = mi;
    if (id == mi) v = -1e30f;
  }

  // fp64 rescore of the 8 candidates
  const float4 q = *reinterpret_cast<const float4*>(feat + (size_t)row * DIM + lane * 4);
  const double inv_i = invn[row];
  double sims[8];
#pragma unroll
  for (int c = 0; c < 8; ++c) {
    const int j = sel[c];
    const float4 f = *reinterpret_cast<const float4*>(feat + (size_t)j * DIM + lane * 4);
    double s = (double)q.x * f.x + (double)q.y * f.y + (double)q.z * f.z + (double)q.w * f.w;
#pragma unroll
    for (int m = 32; m >= 1; m >>= 1) s += __shfl_xor(s, m);
    sims[c] = s * inv_i * invn[j];
  }

  // top-5 of 8 (all lanes identical) + fused output accumulation
  unsigned usedmask = 0;
  float4 o; o.x = o.y = o.z = o.w = 0.f;
#pragma unroll
  for (int t = 0; t < 5; ++t) {
    double best = -1e30; int bc = 0, bj = 0;
#pragma unroll
    for (int c = 0; c < 8; ++c)
      if (!((usedmask >> c) & 1u) && sims[c] > best) { best = sims[c]; bc = c; bj = sel[c]; }
    usedmask |= (1u << bc);
    const float w2 = (float)(best * best);
    const float4 f = *reinterpret_cast<const float4*>(feat + (size_t)bj * DIM + lane * 4);
    o.x += w2 * f.x; o.y += w2 * f.y; o.z += w2 * f.z; o.w += w2 * f.w;
  }
  o.x *= 0.2f; o.y *= 0.2f; o.z *= 0.2f; o.w *= 0.2f;
  *reinterpret_cast<float4*>(out + (size_t)row * DIM + lane * 4) = o;
}

// ---------------------------------------------------------------------------
extern "C" void kernel_launch(void* const* d_in, const int* in_sizes, int n_in,
                              void* d_out, int out_size, void* d_ws, size_t ws_size,
                              hipStream_t stream) {
  const float* feat = (const float*)d_in[0];
  char* ws = (char*)d_ws;

  // phi (8.39 MB) lives in d_out (16.7 MB) until finalize overwrites it.
  unsigned short* phi = (unsigned short*)d_out;
  unsigned short* plo = (unsigned short*)(ws + 0);            // 8,388,608 B
  double*        invn = (double*)(ws + 8388608);              //   131,072 B
  float*        cvalp = (float*)(ws + 8519680);               // 2,097,152 B
  int*          cidxp = (int*)(ws + 10616832);                // 2,097,152 B
  float*          out = (float*)d_out;

  prep_kernel<<<N_ROWS / 8, 256, 0, stream>>>(feat, phi, plo, invn);
  dim3 g2(N_ROWS / 64, RANGES);
  sim_topk_kernel<<<g2, 256, 0, stream>>>(phi, plo, cvalp, cidxp);
  finalize_kernel<<<N_ROWS / 4, 256, 0, stream>>>(feat, invn, cvalp, cidxp, out);
}

// Round 2
// 621.292 us; speedup vs baseline: 1.0950x; 1.0950x over previous
//
#include <hip/hip_runtime.h>

// ============================================================================
// Cosine-sim top-5 weighted gather, N=16384, D=256.
//   sim = normalize(A) @ normalize(A)^T ; top5 per row; out = mean(w^2 * A[idx])
//
// R2: split-bf16 (hi+lo) 3-term MFMA GEMM (err ~1e-6) + BRANCHLESS packed-key
// top-5 queues (index embedded in low 9 mantissa bits, min/max chain insert),
// no barrier in the main loop. Merge -> top-8/range -> fp64 rescore -> gather.
// ============================================================================

#define N_ROWS 16384
#define DIM 256
#define RANGES 4              // j-split of the grid
#define CANDS 32              // 4 ranges * 8 candidates

using bf16x8 = __attribute__((ext_vector_type(8))) short;   // 8 bf16 (4 VGPRs)
using f32x16 = __attribute__((ext_vector_type(16))) float;  // 32x32 acc

static __device__ __forceinline__ unsigned short f32_bf16_rne(float f) {
  unsigned u = __float_as_uint(f);
  u += 0x7fffu + ((u >> 16) & 1u);      // round-to-nearest-even (no NaN inputs)
  return (unsigned short)(u >> 16);
}

// branchless insert of key k into ascending sorted q[0..4] (drops old min)
static __device__ __forceinline__ void ins5(float q[5], float k) {
  q[0] = fmaxf(q[0], fminf(k, q[1]));
  q[1] = fmaxf(q[1], fminf(k, q[2]));
  q[2] = fmaxf(q[2], fminf(k, q[3]));
  q[3] = fmaxf(q[3], fminf(k, q[4]));
  q[4] = fmaxf(q[4], k);
}

// conditional sorted insert (merge phases only; not perf-critical)
static __device__ __forceinline__ void insert8(float tv[8], int ti[8], float v, int j) {
#pragma unroll
  for (int p = 0; p < 7; ++p) {
    const bool shift = (tv[p + 1] < v);
    const bool put   = !shift && (tv[p] < v);
    const float nv = shift ? tv[p + 1] : (put ? v : tv[p]);
    const int   ni = shift ? ti[p + 1] : (put ? j : ti[p]);
    tv[p] = nv; ti[p] = ni;
  }
  if (tv[7] < v) { tv[7] = v; ti[7] = j; }
}

// ---------------------------------------------------------------------------
// Kernel 1: fp64 row norms; write normalized features as bf16 hi/lo pairs in
// MFMA-packed layout: elem(row,k) -> [row>>5][k>>4][(k>>3)&1][row&31][k&7]
// so a 32x32x16 A/B fragment load is lane-contiguous 16B (1 KiB/wave/load).
// ---------------------------------------------------------------------------
__global__ __launch_bounds__(256) void prep_kernel(
    const float* __restrict__ feat,
    unsigned short* __restrict__ phi, unsigned short* __restrict__ plo,
    double* __restrict__ invn) {
  const int tid = threadIdx.x;
  const int sub = tid >> 5;          // 8 sub-groups of 32 lanes, one row each
  const int l32 = tid & 31;
  const int row = blockIdx.x * 8 + sub;

  const float4 a = *reinterpret_cast<const float4*>(feat + (size_t)row * DIM + l32 * 8);
  const float4 b = *reinterpret_cast<const float4*>(feat + (size_t)row * DIM + l32 * 8 + 4);
  double s = (double)a.x * a.x + (double)a.y * a.y + (double)a.z * a.z + (double)a.w * a.w +
             (double)b.x * b.x + (double)b.y * b.y + (double)b.z * b.z + (double)b.w * b.w;
#pragma unroll
  for (int m = 16; m >= 1; m >>= 1) s += __shfl_xor(s, m);   // within 32-lane group
  const double inv = 1.0 / sqrt(s);
  if (l32 == 0) invn[row] = inv;

  float nf[8] = {a.x, a.y, a.z, a.w, b.x, b.y, b.z, b.w};
  unsigned hi[8], lo[8];
#pragma unroll
  for (int e = 0; e < 8; ++e) {
    const float x  = (float)((double)nf[e] * inv);
    const unsigned short h = f32_bf16_rne(x);
    const float hf = __uint_as_float(((unsigned)h) << 16);
    hi[e] = h;
    lo[e] = f32_bf16_rne(x - hf);   // exact residual, then RNE to bf16
  }
  const size_t off = (size_t)(row >> 5) * 8192 + (size_t)(l32 >> 1) * 512 +
                     (size_t)(l32 & 1) * 256 + (size_t)(row & 31) * 8;
  uint4 uh, ul;
  uh.x = hi[0] | (hi[1] << 16); uh.y = hi[2] | (hi[3] << 16);
  uh.z = hi[4] | (hi[5] << 16); uh.w = hi[6] | (hi[7] << 16);
  ul.x = lo[0] | (lo[1] << 16); ul.y = lo[2] | (lo[3] << 16);
  ul.z = lo[4] | (lo[5] << 16); ul.w = lo[6] | (lo[7] << 16);
  *reinterpret_cast<uint4*>(phi + off) = uh;
  *reinterpret_cast<uint4*>(plo + off) = ul;
}

// ---------------------------------------------------------------------------
// Kernel 2: fused split-bf16 GEMM + branchless packed-key top-5 per lane-state.
// Block: 4 waves, SAME 64 query rows i, wave w owns j-strip of 64 per 256-tile.
// D[j][i]: each lane's 16 acc regs belong to ONE query row -> register queues.
// Key = f32 sim with low 9 mantissa bits = (jt<<5)|(r<<1)|pair  (j decodable).
// ---------------------------------------------------------------------------
__global__ __launch_bounds__(256, 2) void sim_topk_kernel(
    const unsigned short* __restrict__ phi, const unsigned short* __restrict__ plo,
    float* __restrict__ cval, int* __restrict__ cidx) {
  __shared__ float sval[40][64];

  const int tid  = threadIdx.x;
  const int wave = tid >> 6;
  const int lane = tid & 63;
  const int hi   = lane >> 5;
  const int iblk = blockIdx.x;     // 64 query rows: iblk*64 ..
  const int range = blockIdx.y;    // j in [range*4096, range*4096+4096)

  const size_t ioff0 = (size_t)(iblk * 2 + 0) * 8192 + (size_t)lane * 8;
  const size_t ioff1 = (size_t)(iblk * 2 + 1) * 8192 + (size_t)lane * 8;

  float tv0[5], tv1[5];
#pragma unroll
  for (int c = 0; c < 5; ++c) { tv0[c] = -1e30f; tv1[c] = -1e30f; }

  for (int jt = 0; jt < 16; ++jt) {
    const int jbase = range * 4096 + jt * 256 + wave * 64;
    const size_t joff0 = (size_t)((jbase >> 5) + 0) * 8192 + (size_t)lane * 8;
    const size_t joff1 = (size_t)((jbase >> 5) + 1) * 8192 + (size_t)lane * 8;

    f32x16 acc00, acc01, acc10, acc11;   // [jf][if]
#pragma unroll
    for (int r = 0; r < 16; ++r) { acc00[r] = 0.f; acc01[r] = 0.f; acc10[r] = 0.f; acc11[r] = 0.f; }

#pragma unroll 2
    for (int kc = 0; kc < 16; ++kc) {
      const size_t ks = (size_t)kc * 512;
      const bf16x8 aj0h = *reinterpret_cast<const bf16x8*>(phi + joff0 + ks);
      const bf16x8 aj1h = *reinterpret_cast<const bf16x8*>(phi + joff1 + ks);
      const bf16x8 aj0l = *reinterpret_cast<const bf16x8*>(plo + joff0 + ks);
      const bf16x8 aj1l = *reinterpret_cast<const bf16x8*>(plo + joff1 + ks);
      const bf16x8 bi0h = *reinterpret_cast<const bf16x8*>(phi + ioff0 + ks);
      const bf16x8 bi1h = *reinterpret_cast<const bf16x8*>(phi + ioff1 + ks);
      const bf16x8 bi0l = *reinterpret_cast<const bf16x8*>(plo + ioff0 + ks);
      const bf16x8 bi1l = *reinterpret_cast<const bf16x8*>(plo + ioff1 + ks);
      // hi*hi
      acc00 = __builtin_amdgcn_mfma_f32_32x32x16_bf16(aj0h, bi0h, acc00, 0, 0, 0);
      acc01 = __builtin_amdgcn_mfma_f32_32x32x16_bf16(aj0h, bi1h, acc01, 0, 0, 0);
      acc10 = __builtin_amdgcn_mfma_f32_32x32x16_bf16(aj1h, bi0h, acc10, 0, 0, 0);
      acc11 = __builtin_amdgcn_mfma_f32_32x32x16_bf16(aj1h, bi1h, acc11, 0, 0, 0);
      // hi*lo
      acc00 = __builtin_amdgcn_mfma_f32_32x32x16_bf16(aj0h, bi0l, acc00, 0, 0, 0);
      acc01 = __builtin_amdgcn_mfma_f32_32x32x16_bf16(aj0h, bi1l, acc01, 0, 0, 0);
      acc10 = __builtin_amdgcn_mfma_f32_32x32x16_bf16(aj1h, bi0l, acc10, 0, 0, 0);
      acc11 = __builtin_amdgcn_mfma_f32_32x32x16_bf16(aj1h, bi1l, acc11, 0, 0, 0);
      // lo*hi
      acc00 = __builtin_amdgcn_mfma_f32_32x32x16_bf16(aj0l, bi0h, acc00, 0, 0, 0);
      acc01 = __builtin_amdgcn_mfma_f32_32x32x16_bf16(aj0l, bi1h, acc01, 0, 0, 0);
      acc10 = __builtin_amdgcn_mfma_f32_32x32x16_bf16(aj1l, bi0h, acc10, 0, 0, 0);
      acc11 = __builtin_amdgcn_mfma_f32_32x32x16_bf16(aj1l, bi1h, acc11, 0, 0, 0);
    }

    // branchless packed-key top-5 update (no index registers, no branches)
    const unsigned msk = 0xFFFFFE00u;
    const int jtc = jt << 5;
#pragma unroll
    for (int r = 0; r < 16; ++r) {
      const unsigned c0 = (unsigned)(jtc | (r << 1));
      const unsigned c1 = c0 | 1u;
      ins5(tv0, __uint_as_float((__float_as_uint(acc00[r]) & msk) | c0));
      ins5(tv1, __uint_as_float((__float_as_uint(acc01[r]) & msk) | c0));
      ins5(tv0, __uint_as_float((__float_as_uint(acc10[r]) & msk) | c1));
      ins5(tv1, __uint_as_float((__float_as_uint(acc11[r]) & msk) | c1));
    }
    // no __syncthreads(): waves free-run, MFMA/VALU phases overlap across waves
  }

  // ---- merge 8 queues x 5 keys per row via LDS ----
  {
    const int slot = (wave * 2 + hi) * 5;
    const int r0 = (lane & 31);
    const int r1 = 32 + (lane & 31);
#pragma unroll
    for (int c = 0; c < 5; ++c) {
      sval[slot + c][r0] = tv0[c];
      sval[slot + c][r1] = tv1[c];
    }
  }
  __syncthreads();
  if (tid < 64) {
    float bv[8]; int bi[8];
#pragma unroll
    for (int c = 0; c < 8; ++c) { bv[c] = -1e30f; bi[c] = 0; }
#pragma unroll
    for (int wv = 0; wv < 4; ++wv)
#pragma unroll
      for (int hh = 0; hh < 2; ++hh)
#pragma unroll
        for (int c = 0; c < 5; ++c) {
          const float v = sval[(wv * 2 + hh) * 5 + c][tid];
          if (v > bv[0]) {
            const unsigned code = __float_as_uint(v) & 0x1FFu;
            const int pair = (int)(code & 1u);
            const int r    = (int)((code >> 1) & 15u);
            const int jt   = (int)(code >> 5);
            const int jl   = (r & 3) + 8 * (r >> 2) + 4 * hh;
            const int j    = range * 4096 + jt * 256 + wv * 64 + pair * 32 + jl;
            insert8(bv, bi, v, j);
          }
        }
    const size_t base = (size_t)(iblk * 64 + tid) * CANDS + range * 8;
#pragma unroll
    for (int c = 0; c < 8; ++c) { cval[base + c] = bv[c]; cidx[base + c] = bi[c]; }
  }
}

// ---------------------------------------------------------------------------
// Kernel 3: per row (one wave): merge 32 candidates -> top-8 by stage-1 key,
// fp64 rescore, top-5, weights^2, fused weighted gather.
// ---------------------------------------------------------------------------
__global__ __launch_bounds__(256) void finalize_kernel(
    const float* __restrict__ feat, const double* __restrict__ invn,
    const float* __restrict__ cval, const int* __restrict__ cidx,
    float* __restrict__ out) {
  const int wave = threadIdx.x >> 6, lane = threadIdx.x & 63;
  const int row = blockIdx.x * 4 + wave;

  float v = -1e30f; int id = -1;
  if (lane < 32) {
    v  = cval[(size_t)row * CANDS + lane];
    id = cidx[(size_t)row * CANDS + lane];
  }
  int sel[8];
#pragma unroll
  for (int c = 0; c < 8; ++c) {
    float mv = v; int mi = id;
#pragma unroll
    for (int m = 32; m >= 1; m >>= 1) {
      const float ov = __shfl_xor(mv, m); const int oi = __shfl_xor(mi, m);
      if (ov > mv || (ov == mv && oi > mi)) { mv = ov; mi = oi; }
    }
    sel[c] = mi;
    if (id == mi) v = -1e30f;
  }

  // fp64 rescore of the 8 candidates
  const float4 q = *reinterpret_cast<const float4*>(feat + (size_t)row * DIM + lane * 4);
  const double inv_i = invn[row];
  double sims[8];
#pragma unroll
  for (int c = 0; c < 8; ++c) {
    const int j = sel[c];
    const float4 f = *reinterpret_cast<const float4*>(feat + (size_t)j * DIM + lane * 4);
    double s = (double)q.x * f.x + (double)q.y * f.y + (double)q.z * f.z + (double)q.w * f.w;
#pragma unroll
    for (int m = 32; m >= 1; m >>= 1) s += __shfl_xor(s, m);
    sims[c] = s * inv_i * invn[j];
  }

  // top-5 of 8 (all lanes identical) + fused output accumulation
  unsigned usedmask = 0;
  float4 o; o.x = o.y = o.z = o.w = 0.f;
#pragma unroll
  for (int t = 0; t < 5; ++t) {
    double best = -1e30; int bc = 0, bj = 0;
#pragma unroll
    for (int c = 0; c < 8; ++c)
      if (!((usedmask >> c) & 1u) && sims[c] > best) { best = sims[c]; bc = c; bj = sel[c]; }
    usedmask |= (1u << bc);
    const float w2 = (float)(best * best);
    const float4 f = *reinterpret_cast<const float4*>(feat + (size_t)bj * DIM + lane * 4);
    o.x += w2 * f.x; o.y += w2 * f.y; o.z += w2 * f.z; o.w += w2 * f.w;
  }
  o.x *= 0.2f; o.y *= 0.2f; o.z *= 0.2f; o.w *= 0.2f;
  *reinterpret_cast<float4*>(out + (size_t)row * DIM + lane * 4) = o;
}

// ---------------------------------------------------------------------------
extern "C" void kernel_launch(void* const* d_in, const int* in_sizes, int n_in,
                              void* d_out, int out_size, void* d_ws, size_t ws_size,
                              hipStream_t stream) {
  const float* feat = (const float*)d_in[0];
  char* ws = (char*)d_ws;

  // phi (8.39 MB) lives in d_out (16.7 MB) until finalize overwrites it.
  unsigned short* phi = (unsigned short*)d_out;
  unsigned short* plo = (unsigned short*)(ws + 0);            // 8,388,608 B
  double*        invn = (double*)(ws + 8388608);              //   131,072 B
  float*        cvalp = (float*)(ws + 8519680);               // 2,097,152 B
  int*          cidxp = (int*)(ws + 10616832);                // 2,097,152 B
  float*          out = (float*)d_out;

  prep_kernel<<<N_ROWS / 8, 256, 0, stream>>>(feat, phi, plo, invn);
  dim3 g2(N_ROWS / 64, RANGES);
  sim_topk_kernel<<<g2, 256, 0, stream>>>(phi, plo, cvalp, cidxp);
  finalize_kernel<<<N_ROWS / 4, 256, 0, stream>>>(feat, invn, cvalp, cidxp, out);
}

// Round 3
// 376.576 us; speedup vs baseline: 1.8065x; 1.6498x over previous
//
#include <hip/hip_runtime.h>

// ============================================================================
// Cosine-sim top-5 weighted gather, N=16384, D=256.
//   sim = normalize(A) @ normalize(A)^T ; top5 per row; out = mean(w^2 * A[idx])
//
// R3: 2-term split-bf16 (hi*hi + hi_j*lo_i, err ~7e-5 rms) MFMA GEMM.
// i-panel (64 rows, hi+lo, 64 KB) staged in LDS once per block (jt-invariant);
// j streams from global as hi-plane only -> L2 demand 32 B/cyc/CU < 56 budget.
// 8 waves/block share the i-panel. Branchless packed-key top-5 queues.
// Merge -> top-8/range -> fp64 rescore of top-8 -> weights^2 gather.
// ============================================================================

#define N_ROWS 16384
#define DIM 256
#define RANGES 4              // j-split of the grid
#define CANDS 32              // 4 ranges * 8 candidates

using bf16x8 = __attribute__((ext_vector_type(8))) short;   // 8 bf16 (4 VGPRs)
using f32x16 = __attribute__((ext_vector_type(16))) float;  // 32x32 acc

static __device__ __forceinline__ unsigned short f32_bf16_rne(float f) {
  unsigned u = __float_as_uint(f);
  u += 0x7fffu + ((u >> 16) & 1u);      // round-to-nearest-even (no NaN inputs)
  return (unsigned short)(u >> 16);
}

// branchless insert of key k into ascending sorted q[0..4] (drops old min)
static __device__ __forceinline__ void ins5(float q[5], float k) {
  q[0] = fmaxf(q[0], fminf(k, q[1]));
  q[1] = fmaxf(q[1], fminf(k, q[2]));
  q[2] = fmaxf(q[2], fminf(k, q[3]));
  q[3] = fmaxf(q[3], fminf(k, q[4]));
  q[4] = fmaxf(q[4], k);
}

// conditional sorted insert (merge phases only; not perf-critical)
static __device__ __forceinline__ void insert8(float tv[8], int ti[8], float v, int j) {
#pragma unroll
  for (int p = 0; p < 7; ++p) {
    const bool shift = (tv[p + 1] < v);
    const bool put   = !shift && (tv[p] < v);
    const float nv = shift ? tv[p + 1] : (put ? v : tv[p]);
    const int   ni = shift ? ti[p + 1] : (put ? j : ti[p]);
    tv[p] = nv; ti[p] = ni;
  }
  if (tv[7] < v) { tv[7] = v; ti[7] = j; }
}

// ---------------------------------------------------------------------------
// Kernel 1: fp64 row norms; write normalized features as bf16 hi/lo pairs in
// MFMA-packed layout: elem(row,k) -> [row>>5][k>>4][(k>>3)&1][row&31][k&7]
// so a 32x32x16 A/B fragment load is lane-contiguous 16B (1 KiB/wave/load).
// ---------------------------------------------------------------------------
__global__ __launch_bounds__(256) void prep_kernel(
    const float* __restrict__ feat,
    unsigned short* __restrict__ phi, unsigned short* __restrict__ plo,
    double* __restrict__ invn) {
  const int tid = threadIdx.x;
  const int sub = tid >> 5;          // 8 sub-groups of 32 lanes, one row each
  const int l32 = tid & 31;
  const int row = blockIdx.x * 8 + sub;

  const float4 a = *reinterpret_cast<const float4*>(feat + (size_t)row * DIM + l32 * 8);
  const float4 b = *reinterpret_cast<const float4*>(feat + (size_t)row * DIM + l32 * 8 + 4);
  double s = (double)a.x * a.x + (double)a.y * a.y + (double)a.z * a.z + (double)a.w * a.w +
             (double)b.x * b.x + (double)b.y * b.y + (double)b.z * b.z + (double)b.w * b.w;
#pragma unroll
  for (int m = 16; m >= 1; m >>= 1) s += __shfl_xor(s, m);   // within 32-lane group
  const double inv = 1.0 / sqrt(s);
  if (l32 == 0) invn[row] = inv;

  float nf[8] = {a.x, a.y, a.z, a.w, b.x, b.y, b.z, b.w};
  unsigned hi[8], lo[8];
#pragma unroll
  for (int e = 0; e < 8; ++e) {
    const float x  = (float)((double)nf[e] * inv);
    const unsigned short h = f32_bf16_rne(x);
    const float hf = __uint_as_float(((unsigned)h) << 16);
    hi[e] = h;
    lo[e] = f32_bf16_rne(x - hf);   // exact residual, then RNE to bf16
  }
  const size_t off = (size_t)(row >> 5) * 8192 + (size_t)(l32 >> 1) * 512 +
                     (size_t)(l32 & 1) * 256 + (size_t)(row & 31) * 8;
  uint4 uh, ul;
  uh.x = hi[0] | (hi[1] << 16); uh.y = hi[2] | (hi[3] << 16);
  uh.z = hi[4] | (hi[5] << 16); uh.w = hi[6] | (hi[7] << 16);
  ul.x = lo[0] | (lo[1] << 16); ul.y = lo[2] | (lo[3] << 16);
  ul.z = lo[4] | (lo[5] << 16); ul.w = lo[6] | (lo[7] << 16);
  *reinterpret_cast<uint4*>(phi + off) = uh;
  *reinterpret_cast<uint4*>(plo + off) = ul;
}

// ---------------------------------------------------------------------------
// Kernel 2: fused 2-term split-bf16 GEMM + branchless packed-key top-5.
// Block: 8 waves, 512 thr. All waves share the block's 64 i-rows (hi+lo in
// LDS, staged once); wave w owns a 64-j strip per jt-tile (512 j per tile).
// D[j][i]: lane's 16 acc regs belong to ONE query row -> register queues.
// Key = f32 sim, low 9 mantissa bits replaced by (jt<<5)|(r<<1)|jf.
// ---------------------------------------------------------------------------
__global__ __launch_bounds__(512, 4) void sim_topk_kernel(
    const unsigned short* __restrict__ phi, const unsigned short* __restrict__ plo,
    float* __restrict__ cval, int* __restrict__ cidx) {
  __shared__ __align__(16) union SharedU {
    struct { unsigned short h[2][8192]; unsigned short l[2][8192]; } p;  // 64 KB
    float sval[80][64];                                                  // 20 KB
  } sh;

  const int tid  = threadIdx.x;
  const int wave = tid >> 6;       // 0..7
  const int lane = tid & 63;
  const int half = lane >> 5;
  const int iblk = blockIdx.x;     // 64 query rows: iblk*64 ..
  const int range = blockIdx.y;    // j in [range*4096, range*4096+4096)
  const int lo8  = lane * 8;       // short offset of this lane's frag chunk

  // ---- stage i-panel (2 row-panels x hi/lo, 64 KB) into LDS ----
  {
    const uint4* shi = reinterpret_cast<const uint4*>(phi + (size_t)iblk * 16384);
    const uint4* slo = reinterpret_cast<const uint4*>(plo + (size_t)iblk * 16384);
    uint4* dhi = reinterpret_cast<uint4*>(&sh.p.h[0][0]);
    uint4* dlo = reinterpret_cast<uint4*>(&sh.p.l[0][0]);
#pragma unroll
    for (int r = 0; r < 4; ++r) {
      dhi[tid + r * 512] = shi[tid + r * 512];
      dlo[tid + r * 512] = slo[tid + r * 512];
    }
  }
  __syncthreads();

  float tv0[5], tv1[5];
#pragma unroll
  for (int c = 0; c < 5; ++c) { tv0[c] = -1e30f; tv1[c] = -1e30f; }

  for (int jt = 0; jt < 8; ++jt) {
    const int jbase = range * 4096 + jt * 512 + wave * 64;
    const unsigned short* jp = phi + (size_t)(jbase >> 5) * 8192 + lo8;

    f32x16 acc00, acc01, acc10, acc11;   // [jf][if]
#pragma unroll
    for (int r = 0; r < 16; ++r) { acc00[r] = 0.f; acc01[r] = 0.f; acc10[r] = 0.f; acc11[r] = 0.f; }

#pragma unroll 2
    for (int kc = 0; kc < 16; ++kc) {
      const int ks = kc * 512;
      const bf16x8 aj0 = *reinterpret_cast<const bf16x8*>(jp + ks);          // j hi, panel 0
      const bf16x8 aj1 = *reinterpret_cast<const bf16x8*>(jp + 8192 + ks);   // j hi, panel 1
      const bf16x8 b0h = *reinterpret_cast<const bf16x8*>(&sh.p.h[0][ks + lo8]);
      const bf16x8 b1h = *reinterpret_cast<const bf16x8*>(&sh.p.h[1][ks + lo8]);
      const bf16x8 b0l = *reinterpret_cast<const bf16x8*>(&sh.p.l[0][ks + lo8]);
      const bf16x8 b1l = *reinterpret_cast<const bf16x8*>(&sh.p.l[1][ks + lo8]);
      // sim ~= hi_j*hi_i + hi_j*lo_i   (err = <lo_j, x_i> ~ 7e-5 rms)
      acc00 = __builtin_amdgcn_mfma_f32_32x32x16_bf16(aj0, b0h, acc00, 0, 0, 0);
      acc00 = __builtin_amdgcn_mfma_f32_32x32x16_bf16(aj0, b0l, acc00, 0, 0, 0);
      acc01 = __builtin_amdgcn_mfma_f32_32x32x16_bf16(aj0, b1h, acc01, 0, 0, 0);
      acc01 = __builtin_amdgcn_mfma_f32_32x32x16_bf16(aj0, b1l, acc01, 0, 0, 0);
      acc10 = __builtin_amdgcn_mfma_f32_32x32x16_bf16(aj1, b0h, acc10, 0, 0, 0);
      acc10 = __builtin_amdgcn_mfma_f32_32x32x16_bf16(aj1, b0l, acc10, 0, 0, 0);
      acc11 = __builtin_amdgcn_mfma_f32_32x32x16_bf16(aj1, b1h, acc11, 0, 0, 0);
      acc11 = __builtin_amdgcn_mfma_f32_32x32x16_bf16(aj1, b1l, acc11, 0, 0, 0);
    }

    // branchless packed-key top-5 update
    const unsigned msk = 0xFFFFFE00u;
#pragma unroll
    for (int r = 0; r < 16; ++r) {
      const unsigned c0 = (unsigned)((jt << 5) | (r << 1));
      ins5(tv0, __uint_as_float((__float_as_uint(acc00[r]) & msk) | c0));
      ins5(tv1, __uint_as_float((__float_as_uint(acc01[r]) & msk) | c0));
      ins5(tv0, __uint_as_float((__float_as_uint(acc10[r]) & msk) | (c0 | 1u)));
      ins5(tv1, __uint_as_float((__float_as_uint(acc11[r]) & msk) | (c0 | 1u)));
    }
    // no barrier: waves free-run; MFMA/VALU phases overlap across waves
  }

  // ---- merge 16 queues x 5 keys per row via LDS (aliased over i-panel) ----
  __syncthreads();   // all waves done reading sh.p before sval overwrites it
  {
    const int slot = (wave * 2 + half) * 5;
    const int r0 = (lane & 31);
    const int r1 = 32 + (lane & 31);
#pragma unroll
    for (int c = 0; c < 5; ++c) {
      sh.sval[slot + c][r0] = tv0[c];
      sh.sval[slot + c][r1] = tv1[c];
    }
  }
  __syncthreads();
  if (tid < 64) {
    float bv[8]; int bi[8];
#pragma unroll
    for (int c = 0; c < 8; ++c) { bv[c] = -1e30f; bi[c] = 0; }
    for (int wv = 0; wv < 8; ++wv)
#pragma unroll
      for (int hh = 0; hh < 2; ++hh)
#pragma unroll
        for (int c = 0; c < 5; ++c) {
          const float v = sh.sval[(wv * 2 + hh) * 5 + c][tid];
          if (v > bv[0]) {
            const unsigned code = __float_as_uint(v) & 0x1FFu;
            const int jf = (int)(code & 1u);
            const int r  = (int)((code >> 1) & 15u);
            const int jt = (int)(code >> 5);
            const int jl = (r & 3) + 8 * (r >> 2) + 4 * hh;
            const int j  = range * 4096 + jt * 512 + wv * 64 + jf * 32 + jl;
            insert8(bv, bi, v, j);
          }
        }
    const size_t base = (size_t)(iblk * 64 + tid) * CANDS + range * 8;
#pragma unroll
    for (int c = 0; c < 8; ++c) { cval[base + c] = bv[c]; cidx[base + c] = bi[c]; }
  }
}

// ---------------------------------------------------------------------------
// Kernel 3: per row (one wave): merge 32 candidates -> top-8 by stage-1 key,
// fp64 rescore, top-5, weights^2, fused weighted gather.
// ---------------------------------------------------------------------------
__global__ __launch_bounds__(256) void finalize_kernel(
    const float* __restrict__ feat, const double* __restrict__ invn,
    const float* __restrict__ cval, const int* __restrict__ cidx,
    float* __restrict__ out) {
  const int wave = threadIdx.x >> 6, lane = threadIdx.x & 63;
  const int row = blockIdx.x * 4 + wave;

  float v = -1e30f; int id = -1;
  if (lane < 32) {
    v  = cval[(size_t)row * CANDS + lane];
    id = cidx[(size_t)row * CANDS + lane];
  }
  int sel[8];
#pragma unroll
  for (int c = 0; c < 8; ++c) {
    float mv = v; int mi = id;
#pragma unroll
    for (int m = 32; m >= 1; m >>= 1) {
      const float ov = __shfl_xor(mv, m); const int oi = __shfl_xor(mi, m);
      if (ov > mv || (ov == mv && oi > mi)) { mv = ov; mi = oi; }
    }
    sel[c] = mi;
    if (id == mi) v = -1e30f;
  }

  // fp64 rescore of the 8 candidates
  const float4 q = *reinterpret_cast<const float4*>(feat + (size_t)row * DIM + lane * 4);
  const double inv_i = invn[row];
  double sims[8];
#pragma unroll
  for (int c = 0; c < 8; ++c) {
    const int j = sel[c];
    const float4 f = *reinterpret_cast<const float4*>(feat + (size_t)j * DIM + lane * 4);
    double s = (double)q.x * f.x + (double)q.y * f.y + (double)q.z * f.z + (double)q.w * f.w;
#pragma unroll
    for (int m = 32; m >= 1; m >>= 1) s += __shfl_xor(s, m);
    sims[c] = s * inv_i * invn[j];
  }

  // top-5 of 8 (all lanes identical) + fused output accumulation
  unsigned usedmask = 0;
  float4 o; o.x = o.y = o.z = o.w = 0.f;
#pragma unroll
  for (int t = 0; t < 5; ++t) {
    double best = -1e30; int bc = 0, bj = 0;
#pragma unroll
    for (int c = 0; c < 8; ++c)
      if (!((usedmask >> c) & 1u) && sims[c] > best) { best = sims[c]; bc = c; bj = sel[c]; }
    usedmask |= (1u << bc);
    const float w2 = (float)(best * best);
    const float4 f = *reinterpret_cast<const float4*>(feat + (size_t)bj * DIM + lane * 4);
    o.x += w2 * f.x; o.y += w2 * f.y; o.z += w2 * f.z; o.w += w2 * f.w;
  }
  o.x *= 0.2f; o.y *= 0.2f; o.z *= 0.2f; o.w *= 0.2f;
  *reinterpret_cast<float4*>(out + (size_t)row * DIM + lane * 4) = o;
}

// ---------------------------------------------------------------------------
extern "C" void kernel_launch(void* const* d_in, const int* in_sizes, int n_in,
                              void* d_out, int out_size, void* d_ws, size_t ws_size,
                              hipStream_t stream) {
  const float* feat = (const float*)d_in[0];
  char* ws = (char*)d_ws;

  // phi (8.39 MB) lives in d_out (16.7 MB) until finalize overwrites it.
  unsigned short* phi = (unsigned short*)d_out;
  unsigned short* plo = (unsigned short*)(ws + 0);            // 8,388,608 B
  double*        invn = (double*)(ws + 8388608);              //   131,072 B
  float*        cvalp = (float*)(ws + 8519680);               // 2,097,152 B
  int*          cidxp = (int*)(ws + 10616832);                // 2,097,152 B
  float*          out = (float*)d_out;

  prep_kernel<<<N_ROWS / 8, 256, 0, stream>>>(feat, phi, plo, invn);
  dim3 g2(N_ROWS / 64, RANGES);
  sim_topk_kernel<<<g2, 512, 0, stream>>>(phi, plo, cvalp, cidxp);
  finalize_kernel<<<N_ROWS / 4, 256, 0, stream>>>(feat, invn, cvalp, cidxp, out);
}